// Round 14
// baseline (273.901 us; speedup 1.0000x reference)
//
#include <hip/hip_runtime.h>
#include <math.h>

#define PI_F 3.14159265358979323846f

typedef float v2f __attribute__((ext_vector_type(2)));

// ---------------------------------------------------------------------------
// GF(2) deferred-CNOT + 6-GATE fusion (R14), all tables at compile time.
// CNOTs are index relabelings in M / M^-1; Rot on wire w pairs p <-> p^col[w],
// role = parity(p & row[w]); biorthogonality parity(col_j & row_i) = d_ij.
// Layer-0 Rots fold into the init.
// Per pass: 6 same-layer gates. 4 "reg" gates -> in-register butterfly levels
// (masks m0..m3, gray-chain LDS); 2 "cross" gates -> DPP quad_perm lane^1 /
// lane^2 levels (side = t&1 / t&2). Representative q = (t&1)m4 ^ (t&2)m5 ^
// sum t_{2+i} nb_i with nb in the nullspace of ALL SIX roles -> reg levels
// use raw coefficients; cross sides are exactly t&1 / t&2.
// Bank coverage: nb chosen (RREF over low-4 cols + greedy, best cross pair)
// so the lane->low4(q) map has max rank (4 -> b64 conflict floor).
// 10 passes (vs 15): LDS traffic -33%.
// ---------------------------------------------------------------------------
struct Tab {
    unsigned gmask[10][4];          // reg pairing masks m0..m3
    unsigned m45[10][2];            // cross masks (t bit0, t bit1)
    int      ggate[10][6];          // gate idx; lev 0-3 reg, 4-5 cross
    unsigned short qtab[10][256];   // baked representative per (pass, thread)
    unsigned zrow[12];              // final measurement parity rows
};

constexpr int nullspace12(const unsigned* rows, int nr, unsigned* out) {
    unsigned R[8] = {};
    for (int i = 0; i < nr; ++i) R[i] = rows[i];
    int pivc[8] = {};
    int rank = 0;
    for (int c = 11; c >= 0; --c) {
        int sel = -1;
        for (int i = rank; i < nr; ++i) if ((R[i] >> c) & 1u) { sel = i; break; }
        if (sel < 0) continue;
        unsigned tmp = R[rank]; R[rank] = R[sel]; R[sel] = tmp;
        for (int i = 0; i < nr; ++i)
            if (i != rank && ((R[i] >> c) & 1u)) R[i] ^= R[rank];
        pivc[rank] = c; ++rank;
    }
    int nn = 0;
    for (int c = 0; c < 12; ++c) {
        bool isp = false;
        for (int i = 0; i < rank; ++i) if (pivc[i] == c) isp = true;
        if (isp) continue;
        unsigned v = 1u << c;
        for (int i = 0; i < rank; ++i)
            if ((R[i] >> c) & 1u) v |= 1u << pivc[i];
        out[nn++] = v;
    }
    return nn;
}

// reduce x (low4) against a row-echelon set bas[0..n); 4 sweeps = fixpoint
constexpr unsigned red4(const unsigned* bas, int n, unsigned x) {
    unsigned r = x & 15u;
    for (int sweep = 0; sweep < 4; ++sweep) {
        for (int i = 0; i < n; ++i) {
            const unsigned b = bas[i] & 15u;
            unsigned hb = 0;
            for (int c = 3; c >= 0; --c) if ((b >> c) & 1u) { hb = 1u << c; break; }
            if (r & hb) r ^= b;
        }
    }
    return r;
}

// full RREF of v[0..n) over columns 0..3 (in place); pivrow[c] = row or -1
constexpr void rref_low4(unsigned* v, int n, int* pivrow) {
    bool used[8] = {};
    for (int c = 0; c < 4; ++c) {
        pivrow[c] = -1;
        int sel = -1;
        for (int i = 0; i < n; ++i)
            if (!used[i] && ((v[i] >> c) & 1u)) { sel = i; break; }
        if (sel < 0) continue;
        for (int i = 0; i < n; ++i)
            if (i != sel && ((v[i] >> c) & 1u)) v[i] ^= v[sel];
        used[sel] = true; pivrow[c] = sel;
    }
}

constexpr Tab make_tab() {
    Tab tb{};
    unsigned col[12] = {}, row[12] = {};
    for (int w = 0; w < 12; ++w) { col[w] = 1u << (11 - w); row[w] = 1u << (11 - w); }
    for (int w = 0; w < 12; ++w) {           // layer-0 CNOTs (Rots in init)
        const int c = w, tg = (w + 1) % 12;
        col[c] ^= col[tg];
        row[tg] ^= row[c];
    }
    int pass = 0;
    for (int l = 1; l < 6; ++l) {
        for (int grp = 0; grp < 2; ++grp) {
            unsigned gm[6] = {}, gr[6] = {};
            for (int i = 0; i < 6; ++i) {
                gm[i] = col[grp * 6 + i];
                gr[i] = row[grp * 6 + i];
            }
            unsigned N6[8] = {};
            nullspace12(gr, 6, N6);          // 6-dim (roles independent)
            unsigned vv[6] = {};
            for (int i = 0; i < 6; ++i) vv[i] = N6[i];
            int pivrow[4] = {};
            rref_low4(vv, 6, pivrow);        // pivot rows realize low4-span
            // ---- choose cross pair maximizing lane->bank-pair rank ----------
            int bestScore = -1, ba = 4, bb = 5;
            unsigned bestnb[6] = {};
            for (int a = 0; a < 6; ++a) {
                for (int b2 = a + 1; b2 < 6; ++b2) {
                    unsigned bas4[4] = {};
                    int ncov = 0;
                    { const unsigned r = red4(bas4, ncov, gm[a]);
                      if (r) bas4[ncov++] = r; }
                    { const unsigned r = red4(bas4, ncov, gm[b2]);
                      if (r) bas4[ncov++] = r; }
                    int score = ncov;
                    unsigned nbt[6] = {};
                    int ns = 0;
                    bool rowused[6] = {};
                    // pivot rows that extend coverage
                    for (int c = 0; c < 4 && ns < 4; ++c) {
                        if (pivrow[c] < 0) continue;
                        const unsigned x = vv[pivrow[c]];
                        const unsigned r = red4(bas4, ncov, x);
                        if (r) {
                            bas4[ncov++] = r; ++score;
                            nbt[ns++] = x; rowused[pivrow[c]] = true;
                        }
                    }
                    // fill remaining lane slots: prefer kernel rows (low4==0)
                    for (int i = 0; i < 6 && ns < 4; ++i) {
                        if (rowused[i] || (vv[i] & 15u) != 0u) continue;
                        nbt[ns++] = vv[i]; rowused[i] = true;
                    }
                    for (int i = 0; i < 6 && ns < 4; ++i) {
                        if (rowused[i]) continue;
                        nbt[ns++] = vv[i]; rowused[i] = true;
                    }
                    // wave slots
                    for (int i = 0; i < 6 && ns < 6; ++i) {
                        if (rowused[i]) continue;
                        nbt[ns++] = vv[i]; rowused[i] = true;
                    }
                    if (score > bestScore) {
                        bestScore = score; ba = a; bb = b2;
                        for (int i = 0; i < 6; ++i) bestnb[i] = nbt[i];
                    }
                }
            }
            // ---- emit pass tables -------------------------------------------
            int nr = 0;
            for (int i = 0; i < 6; ++i) {
                if (i == ba || i == bb) continue;
                tb.gmask[pass][nr] = gm[i];
                tb.ggate[pass][nr] = l * 12 + grp * 6 + i;
                ++nr;
            }
            tb.ggate[pass][4] = l * 12 + grp * 6 + ba;
            tb.ggate[pass][5] = l * 12 + grp * 6 + bb;
            tb.m45[pass][0] = gm[ba];
            tb.m45[pass][1] = gm[bb];
            for (int t = 0; t < 256; ++t) {
                unsigned q = 0u;
                if (t & 1) q ^= gm[ba];
                if (t & 2) q ^= gm[bb];
                for (int i = 0; i < 6; ++i)
                    if (t & (4 << i)) q ^= bestnb[i];
                tb.qtab[pass][t] = (unsigned short)q;
            }
            ++pass;
        }
        const int r = l + 1;
        for (int w = 0; w < 12; ++w) {
            const int c = w, tg = (w + r) % 12;
            col[c] ^= col[tg];
            row[tg] ^= row[c];
        }
    }
    for (int w = 0; w < 12; ++w) tb.zrow[w] = row[w];
    return tb;
}

__constant__ Tab GT = make_tab();

// pass-ordered Rot coefs: [pass*48 + lev*8 + j] (10 passes, 6 levels);
// layer-0 gates at [480 + w*8 + j]. Written each call by rot_coef_kernel.
__device__ float g_coef[576];

__device__ __forceinline__ void rot8(const float* __restrict__ wp, float* o) {
    const float phi = wp[0], th = wp[1], om = wp[2];
    const float hs = 0.5f * (phi + om), hd = 0.5f * (phi - om), ht = 0.5f * th;
    const float ctt = cosf(ht), stt = sinf(ht);
    const float cs = cosf(hs), ss = sinf(hs);
    const float cd = cosf(hd), sd = sinf(hd);
    o[0] = cs * ctt;  o[1] = -ss * ctt;   // u00
    o[2] = -cd * stt; o[3] = -sd * stt;   // u01
    o[4] = cd * stt;  o[5] = -sd * stt;   // u10
    o[6] = cs * ctt;  o[7] = ss * ctt;    // u11
}

__global__ void rot_coef_kernel(const float* __restrict__ weights) {
    const int i = blockIdx.x * blockDim.x + threadIdx.x;
    if (i < 60) {
        const int ps = i / 6, lev = i % 6;
        const int g = GT.ggate[ps][lev];
        float o[8];
        rot8(weights + g * 3, o);
        #pragma unroll
        for (int j = 0; j < 8; ++j) g_coef[ps * 48 + lev * 8 + j] = o[j];
    } else if (i >= 64 && i < 76) {
        const int w = i - 64;
        float o[8];
        rot8(weights + w * 3, o);
        #pragma unroll
        for (int j = 0; j < 8; ++j) g_coef[480 + w * 8 + j] = o[j];
    }
}

__device__ __forceinline__ v2f cmulv(v2f A, v2f B) {
    return (v2f){ A.x * B.x - A.y * B.y, A.x * B.y + A.y * B.x };
}

// packed complex butterfly (v_pk_fma_f32 path, R11)
__device__ __forceinline__ void bf(v2f& X, v2f& Y,
                                   float Ar, float Ai, float Br, float Bi,
                                   float Cr, float Ci, float Dr, float Di) {
    const v2f x = X, y = Y;
    const v2f xs = { -x.y, x.x };
    const v2f ys = { -y.y, y.x };
    v2f nx = x * (v2f){ Ar, Ar };
    nx = __builtin_elementwise_fma((v2f){ Ai, Ai }, xs, nx);
    nx = __builtin_elementwise_fma((v2f){ Br, Br }, y,  nx);
    nx = __builtin_elementwise_fma((v2f){ Bi, Bi }, ys, nx);
    v2f ny = x * (v2f){ Cr, Cr };
    ny = __builtin_elementwise_fma((v2f){ Ci, Ci }, xs, ny);
    ny = __builtin_elementwise_fma((v2f){ Dr, Dr }, y,  ny);
    ny = __builtin_elementwise_fma((v2f){ Di, Di }, ys, ny);
    X = nx; Y = ny;
}

// cross-lane fetch via DPP quad_perm (VALU pipe, no LDS traffic)
template <int CTRL>
__device__ __forceinline__ float dpp_f(float x) {
    return __int_as_float(
        __builtin_amdgcn_mov_dpp(__float_as_int(x), CTRL, 0xF, 0xF, true));
}

// ---------------------------------------------------------------------------
// One block (256 threads) per batch element. LDS = exactly the 32 KB state.
// 10 fused passes (6 gates each): gray-chain b64 LDS, 4 packed reg levels,
// 2 packed DPP cross levels. Named registers + opaque asm (R5/R7 lessons).
// ---------------------------------------------------------------------------
__global__ __launch_bounds__(256) void qvl_fused(
    const float* __restrict__ v,        // (B, 512)
    const float* __restrict__ Wc,       // (12, 512)
    const float* __restrict__ bc,       // (12,)
    float* __restrict__ out)            // (B, 12)
{
    __shared__ v2f st[4096];     // 32768 B total LDS
    float* redf = reinterpret_cast<float*>(st);   // overlay (48 floats)

    const int t    = threadIdx.x;
    const int lane = t & 63;
    const int wv   = t >> 6;
    const int b    = blockIdx.x;

    // ---- x_w = tanh(v[b] . Wc[w] + bc[w]) * pi (partials into overlay) -----
    {
        const float2 vv = reinterpret_cast<const float2*>(v + b * 512)[t];
        #pragma unroll
        for (int w = 0; w < 12; ++w) {
            const float2 ww = reinterpret_cast<const float2*>(Wc + w * 512)[t];
            float p = vv.x * ww.x + vv.y * ww.y;
            #pragma unroll
            for (int s = 1; s < 64; s <<= 1) p += __shfl_xor(p, s, 64);
            if (lane == 0) redf[w * 4 + wv] = p;
        }
    }
    __syncthreads();

    // ---- per-wave: lanes 0..11 fold RY(x_w) + layer-0 Rot into (aw, bw) ----
    float awx = 0.0f, awy = 0.0f, bwx = 0.0f, bwy = 0.0f;
    if (lane < 12) {
        const float x = tanhf(redf[lane * 4 + 0] + redf[lane * 4 + 1] +
                              redf[lane * 4 + 2] + redf[lane * 4 + 3] + bc[lane]) * PI_F;
        const float h = 0.5f * x;
        const float c = cosf(h), s = sinf(h);
        const float* c8 = g_coef + 480 + lane * 8;
        awx = c8[0] * c + c8[2] * s;  awy = c8[1] * c + c8[3] * s;
        bwx = c8[4] * c + c8[6] * s;  bwy = c8[5] * c + c8[7] * s;
    }
    __syncthreads();   // overlay reads done before init overwrites st

    // ---- init: product state; p = k*256 + t (t bits -> wires 11..4) --------
    {
        v2f hi = { 1.0f, 0.0f };
        #pragma unroll
        for (int j = 0; j < 8; ++j) {
            const int src = 11 - j;            // wire for p bit j
            const float ax = __shfl(awx, src, 64), ay = __shfl(awy, src, 64);
            const float bx = __shfl(bwx, src, 64), by = __shfl(bwy, src, 64);
            const int bit = (t >> j) & 1;
            hi = cmulv(hi, (v2f){ bit ? bx : ax, bit ? by : ay });
        }
        v2f A3 = { __shfl(awx, 3, 64), __shfl(awy, 3, 64) };
        v2f B3 = { __shfl(bwx, 3, 64), __shfl(bwy, 3, 64) };
        v2f A2 = { __shfl(awx, 2, 64), __shfl(awy, 2, 64) };
        v2f B2 = { __shfl(bwx, 2, 64), __shfl(bwy, 2, 64) };
        v2f A1 = { __shfl(awx, 1, 64), __shfl(awy, 1, 64) };
        v2f B1 = { __shfl(bwx, 1, 64), __shfl(bwy, 1, 64) };
        v2f A0 = { __shfl(awx, 0, 64), __shfl(awy, 0, 64) };
        v2f B0 = { __shfl(bwx, 0, 64), __shfl(bwy, 0, 64) };
        v2f fA[4], fB[4];
        #pragma unroll
        for (int m = 0; m < 4; ++m) {
            fA[m] = cmulv((m & 1) ? B3 : A3, (m & 2) ? B2 : A2);   // p bits 8,9
            fB[m] = cmulv((m & 1) ? B1 : A1, (m & 2) ? B0 : A0);   // p bits 10,11
        }
        #pragma unroll
        for (int k = 0; k < 16; ++k)
            st[k * 256 + t] = cmulv(hi, cmulv(fA[k & 3], fB[k >> 2]));
    }

    // ---- 10 fused passes (layers 1..5, 6 gates each) ------------------------
    unsigned qn = GT.qtab[0][t];
    #pragma unroll 1
    for (int ps = 0; ps < 10; ++ps) {
        unsigned q = qn;
        qn = GT.qtab[(ps + 1 < 10) ? ps + 1 : 0][t];   // prefetch next
        __syncthreads();
        const float* cp = g_coef + ps * 48;    // uniform -> s_load
        const unsigned m0 = GT.gmask[ps][0], m1 = GT.gmask[ps][1];
        const unsigned m2 = GT.gmask[ps][2], m3 = GT.gmask[ps][3];

        // Gray-code load chain (one rolling address register)
        unsigned ad = q;
        v2f g0  = st[ad]; ad ^= m0;
        v2f g1  = st[ad]; ad ^= m1;
        v2f g3  = st[ad]; ad ^= m0;
        v2f g2  = st[ad]; ad ^= m2;
        v2f g6  = st[ad]; ad ^= m0;
        v2f g7  = st[ad]; ad ^= m1;
        v2f g5  = st[ad]; ad ^= m0;
        v2f g4  = st[ad]; ad ^= m3;
        v2f g12 = st[ad]; ad ^= m0;
        v2f g13 = st[ad]; ad ^= m1;
        v2f g15 = st[ad]; ad ^= m0;
        v2f g14 = st[ad]; ad ^= m2;
        v2f g10 = st[ad]; ad ^= m0;
        v2f g11 = st[ad]; ad ^= m1;
        v2f g9  = st[ad]; ad ^= m0;
        v2f g8  = st[ad];

        // ---- 4 in-register levels: raw coefs (parity-0 representatives) ----
        #define BF(X, Y) bf(X, Y, Ar, Ai, Br, Bi, Cr, Ci, Dr, Di)
        { const float Ar = cp[0],  Ai = cp[1],  Br = cp[2],  Bi = cp[3];
          const float Cr = cp[4],  Ci = cp[5],  Dr = cp[6],  Di = cp[7];
          BF(g0,g1); BF(g2,g3); BF(g4,g5); BF(g6,g7);
          BF(g8,g9); BF(g10,g11); BF(g12,g13); BF(g14,g15); }
        { const float Ar = cp[8],  Ai = cp[9],  Br = cp[10], Bi = cp[11];
          const float Cr = cp[12], Ci = cp[13], Dr = cp[14], Di = cp[15];
          BF(g0,g2); BF(g1,g3); BF(g4,g6); BF(g5,g7);
          BF(g8,g10); BF(g9,g11); BF(g12,g14); BF(g13,g15); }
        { const float Ar = cp[16], Ai = cp[17], Br = cp[18], Bi = cp[19];
          const float Cr = cp[20], Ci = cp[21], Dr = cp[22], Di = cp[23];
          BF(g0,g4); BF(g1,g5); BF(g2,g6); BF(g3,g7);
          BF(g8,g12); BF(g9,g13); BF(g10,g14); BF(g11,g15); }
        { const float Ar = cp[24], Ai = cp[25], Br = cp[26], Bi = cp[27];
          const float Cr = cp[28], Ci = cp[29], Dr = cp[30], Di = cp[31];
          BF(g0,g8); BF(g1,g9); BF(g2,g10); BF(g3,g11);
          BF(g4,g12); BF(g5,g13); BF(g6,g14); BF(g7,g15); }
        #undef BF

        // ---- cross level 4: partner lane^1 (quad_perm 0xB1), side = t&1 ----
        {
            const bool s_ = (t & 1) != 0;
            const float Pr = s_ ? cp[38] : cp[32];
            const float Pi = s_ ? cp[39] : cp[33];
            const float Qr = s_ ? cp[36] : cp[34];
            const float Qi = s_ ? cp[37] : cp[35];
            #define XAMP(G) { \
                v2f ov; ov.x = dpp_f<0xB1>(G.x); ov.y = dpp_f<0xB1>(G.y); \
                const v2f gs = { -G.y, G.x }; \
                const v2f os = { -ov.y, ov.x }; \
                v2f n = G * (v2f){ Pr, Pr }; \
                n = __builtin_elementwise_fma((v2f){ Pi, Pi }, gs, n); \
                n = __builtin_elementwise_fma((v2f){ Qr, Qr }, ov, n); \
                n = __builtin_elementwise_fma((v2f){ Qi, Qi }, os, n); \
                G = n; }
            XAMP(g0) XAMP(g1) XAMP(g2) XAMP(g3) XAMP(g4) XAMP(g5) XAMP(g6) XAMP(g7)
            XAMP(g8) XAMP(g9) XAMP(g10) XAMP(g11) XAMP(g12) XAMP(g13) XAMP(g14) XAMP(g15)
            #undef XAMP
        }
        // ---- cross level 5: partner lane^2 (quad_perm 0x4E), side = t&2 ----
        {
            const bool s_ = (t & 2) != 0;
            const float Pr = s_ ? cp[46] : cp[40];
            const float Pi = s_ ? cp[47] : cp[41];
            const float Qr = s_ ? cp[44] : cp[42];
            const float Qi = s_ ? cp[45] : cp[43];
            #define XAMP(G) { \
                v2f ov; ov.x = dpp_f<0x4E>(G.x); ov.y = dpp_f<0x4E>(G.y); \
                const v2f gs = { -G.y, G.x }; \
                const v2f os = { -ov.y, ov.x }; \
                v2f n = G * (v2f){ Pr, Pr }; \
                n = __builtin_elementwise_fma((v2f){ Pi, Pi }, gs, n); \
                n = __builtin_elementwise_fma((v2f){ Qr, Qr }, ov, n); \
                n = __builtin_elementwise_fma((v2f){ Qi, Qi }, os, n); \
                G = n; }
            XAMP(g0) XAMP(g1) XAMP(g2) XAMP(g3) XAMP(g4) XAMP(g5) XAMP(g6) XAMP(g7)
            XAMP(g8) XAMP(g9) XAMP(g10) XAMP(g11) XAMP(g12) XAMP(g13) XAMP(g14) XAMP(g15)
            #undef XAMP
        }

        // opaque barrier on q: store chain recomputed, not CSE'd with loads
        asm volatile("" : "+v"(q));

        ad = q;
        st[ad] = g0;  ad ^= m0;
        st[ad] = g1;  ad ^= m1;
        st[ad] = g3;  ad ^= m0;
        st[ad] = g2;  ad ^= m2;
        st[ad] = g6;  ad ^= m0;
        st[ad] = g7;  ad ^= m1;
        st[ad] = g5;  ad ^= m0;
        st[ad] = g4;  ad ^= m3;
        st[ad] = g12; ad ^= m0;
        st[ad] = g13; ad ^= m1;
        st[ad] = g15; ad ^= m0;
        st[ad] = g14; ad ^= m2;
        st[ad] = g10; ad ^= m0;
        st[ad] = g11; ad ^= m1;
        st[ad] = g9;  ad ^= m0;
        st[ad] = g8;
    }
    __syncthreads();

    // ---- PauliZ expvals; p = k*256 + t, sign = parity(p & zrow) ------------
    float p2[16];
    #pragma unroll
    for (int k = 0; k < 16; ++k) {
        const v2f aa = st[k * 256 + t];
        p2[k] = aa.x * aa.x + aa.y * aa.y;
    }
    __syncthreads();   // all st reads done before overlay reuse
    #pragma unroll
    for (int w = 0; w < 12; ++w) {
        const unsigned zr = GT.zrow[w];
        const unsigned Aw = (unsigned)__popc((unsigned)t & zr) & 1u;
        const unsigned nm = (zr >> 8) & 0xFu;
        unsigned P = 0u;
        P ^= (nm & 1u) ? 0xAAAAu : 0u;
        P ^= (nm & 2u) ? 0xCCCCu : 0u;
        P ^= (nm & 4u) ? 0xF0F0u : 0u;
        P ^= (nm & 8u) ? 0xFF00u : 0u;
        P ^= Aw ? 0xFFFFu : 0u;
        float z = 0.0f;
        #pragma unroll
        for (int k = 0; k < 16; ++k)
            z += ((P >> k) & 1u) ? -p2[k] : p2[k];
        #pragma unroll
        for (int s = 1; s < 64; s <<= 1) z += __shfl_xor(z, s, 64);
        if (lane == 0) redf[w * 4 + wv] = z;
    }
    __syncthreads();
    if (t < 12)
        out[b * 12 + t] = redf[t * 4 + 0] + redf[t * 4 + 1] +
                          redf[t * 4 + 2] + redf[t * 4 + 3];
}

extern "C" void kernel_launch(void* const* d_in, const int* in_sizes, int n_in,
                              void* d_out, int out_size, void* d_ws, size_t ws_size,
                              hipStream_t stream) {
    (void)n_in; (void)out_size; (void)d_ws; (void)ws_size;
    const float* v   = (const float*)d_in[0];
    const float* Wc  = (const float*)d_in[1];
    const float* bc  = (const float*)d_in[2];
    const float* wts = (const float*)d_in[3];
    float* out = (float*)d_out;

    const int B = in_sizes[0] / 512;
    rot_coef_kernel<<<1, 128, 0, stream>>>(wts);
    qvl_fused<<<B, 256, 0, stream>>>(v, Wc, bc, out);
}

// Round 15
// 253.885 us; speedup vs baseline: 1.0788x; 1.0788x over previous
//
#include <hip/hip_runtime.h>
#include <math.h>

#define PI_F 3.14159265358979323846f

typedef float v2f __attribute__((ext_vector_type(2)));
typedef float v4f __attribute__((ext_vector_type(4)));

// ---------------------------------------------------------------------------
// GF(2) deferred-CNOT + 4-gate fusion + DOUBLE-LAYOUT passes (R15).
// Pass k+1's layout L_{k+1}: amp p lives at v2f addr = posHi*512 + t*2 + posLo
// where (t, pos) solve p = q_{k+1}(t) ^ combo(pos), pos bit0 -> m0 (addr bit0),
// pos bits1-3 -> m1..m3 (addr bits 9..11), t bits 0..7 -> addr bits 1..8.
// Pass k STORES into L_{k+1} (gray chain, masks sm_j = L_{k+1}(m_j), base
// qstore[k][t] = L_{k+1}(q_k(t))); pass k+1 LOADS are then 8x ds_read_b128 at
// t*16B + h*4096B: coalesced, conflict-free, no address math. L_15 = identity
// so the readout reads st[p] directly. All maps built constexpr; store-side
// bank coverage enforced by image-space low-4 RREF of each nullspace basis.
// ---------------------------------------------------------------------------
struct Tab {
    int      ggate[15][4];           // gate index (layer*12 + wire)
    unsigned smask[15][4];           // store gray-chain masks L_{k+1}(m_j)
    unsigned short qstore[15][256];  // store base L_{k+1}(q_k(t))
    unsigned short init_t[256];      // L_0(t)
    unsigned short initk[16];        // L_0(k<<8)
    unsigned zrow[12];               // final measurement parity rows
};

constexpr int nullspace12(const unsigned* rows, int nr, unsigned* out) {
    unsigned R[8] = {};
    for (int i = 0; i < nr; ++i) R[i] = rows[i];
    int pivc[8] = {};
    int rank = 0;
    for (int c = 11; c >= 0; --c) {
        int sel = -1;
        for (int i = rank; i < nr; ++i) if ((R[i] >> c) & 1u) { sel = i; break; }
        if (sel < 0) continue;
        unsigned tmp = R[rank]; R[rank] = R[sel]; R[sel] = tmp;
        for (int i = 0; i < nr; ++i)
            if (i != rank && ((R[i] >> c) & 1u)) R[i] ^= R[rank];
        pivc[rank] = c; ++rank;
    }
    int nn = 0;
    for (int c = 0; c < 12; ++c) {
        bool isp = false;
        for (int i = 0; i < rank; ++i) if (pivc[i] == c) isp = true;
        if (isp) continue;
        unsigned v = 1u << c;
        for (int i = 0; i < rank; ++i)
            if ((R[i] >> c) & 1u) v |= 1u << pivc[i];
        out[nn++] = v;
    }
    return nn;
}

// linear map given by basis B[12] -> images I[12]; rows kept sorted by
// leading bit descending so a single ordered pass reduces any x.
struct LMap {
    unsigned eb[12];   // echelon basis rows
    unsigned ei[12];   // their images
    unsigned lb[12];   // leading bit of eb
    int n;
};

constexpr unsigned lead_bit(unsigned v) {
    unsigned lb = 0;
    for (int c = 11; c >= 0; --c) if ((v >> c) & 1u) { lb = 1u << c; break; }
    return lb;
}

constexpr LMap build_lmap(const unsigned* B, const unsigned* I) {
    LMap m{};
    m.n = 0;
    for (int i = 0; i < 12; ++i) {
        unsigned v = B[i], im = I[i];
        for (int j = 0; j < m.n; ++j)          // sorted descending -> one pass
            if (v & m.lb[j]) { v ^= m.eb[j]; im ^= m.ei[j]; }
        if (!v) continue;
        const unsigned l = lead_bit(v);
        int pos = m.n;
        while (pos > 0 && m.lb[pos - 1] < l) {
            m.eb[pos] = m.eb[pos - 1]; m.ei[pos] = m.ei[pos - 1]; m.lb[pos] = m.lb[pos - 1];
            --pos;
        }
        m.eb[pos] = v; m.ei[pos] = im; m.lb[pos] = l;
        ++m.n;
    }
    return m;
}

constexpr unsigned lmap_apply(const LMap& m, unsigned x) {
    unsigned r = x, acc = 0;
    for (int j = 0; j < m.n; ++j)
        if (r & m.lb[j]) { r ^= m.eb[j]; acc ^= m.ei[j]; }
    return acc;   // r == 0 whenever x is in the span (basis is full rank 12)
}

constexpr Tab make_tab() {
    Tab tb{};
    unsigned col[12] = {}, row[12] = {};
    for (int w = 0; w < 12; ++w) { col[w] = 1u << (11 - w); row[w] = 1u << (11 - w); }
    for (int w = 0; w < 12; ++w) {           // layer-0 CNOTs (Rots in init)
        const int c = w, tg = (w + 1) % 12;
        col[c] ^= col[tg];
        row[tg] ^= row[c];
    }
    unsigned pm[15][4] = {}, pr[15][4] = {};
    {
        int pass = 0;
        for (int l = 1; l < 6; ++l) {
            for (int grp = 0; grp < 3; ++grp) {
                for (int i = 0; i < 4; ++i) {
                    const int w = grp * 4 + i;
                    pm[pass][i] = col[w];
                    pr[pass][i] = row[w];
                    tb.ggate[pass][i] = l * 12 + w;
                }
                ++pass;
            }
            const int r = l + 1;
            for (int w = 0; w < 12; ++w) {
                const int c = w, tg = (w + r) % 12;
                col[c] ^= col[tg];
                row[tg] ^= row[c];
            }
        }
        for (int w = 0; w < 12; ++w) tb.zrow[w] = row[w];
    }
    // image bit assignment of layout L_k: nb_i -> addr bit 1+i, m0 -> bit 0,
    // m1..m3 -> bits 9..11.
    unsigned nbf[15][8] = {};
    for (int ps = 14; ps >= 0; --ps) {
        unsigned nbr[8] = {};
        nullspace12(pr[ps], 4, nbr);         // dim 8 (roles independent)
        unsigned w_[8] = {};
        LMap lm{};
        bool have_lm = false;
        if (ps == 14) {
            for (int i = 0; i < 8; ++i) w_[i] = nbr[i];   // L_15 = identity
        } else {
            unsigned B[12] = {}, I[12] = {};
            for (int i = 0; i < 8; ++i) { B[i] = nbf[ps + 1][i]; I[i] = 1u << (1 + i); }
            B[8] = pm[ps + 1][0]; I[8] = 1u;
            B[9] = pm[ps + 1][1]; I[9] = 512u;
            B[10] = pm[ps + 1][2]; I[10] = 1024u;
            B[11] = pm[ps + 1][3]; I[11] = 2048u;
            lm = build_lmap(B, I);
            have_lm = true;
            for (int i = 0; i < 8; ++i) w_[i] = lmap_apply(lm, nbr[i]);
        }
        // simultaneous low-4 RREF on (w_, nbr): store-side bank coverage
        int pivrow[4] = { -1, -1, -1, -1 };
        bool used[8] = {};
        for (int c = 0; c < 4; ++c) {
            int sel = -1;
            for (int i = 0; i < 8; ++i)
                if (!used[i] && ((w_[i] >> c) & 1u)) { sel = i; break; }
            if (sel < 0) continue;
            for (int i = 0; i < 8; ++i)
                if (i != sel && ((w_[i] >> c) & 1u)) { w_[i] ^= w_[sel]; nbr[i] ^= nbr[sel]; }
            used[sel] = true; pivrow[c] = sel;
        }
        unsigned fw[8] = {}, fn[8] = {};
        bool slot[8] = {}, ru[8] = {};
        for (int c = 0; c < 4; ++c)
            if (pivrow[c] >= 0) {
                fw[c] = w_[pivrow[c]]; fn[c] = nbr[pivrow[c]];
                ru[pivrow[c]] = true; slot[c] = true;
            }
        int fs = 0;
        for (int i = 0; i < 8; ++i) {
            if (ru[i]) continue;
            while (fs < 8 && slot[fs]) ++fs;
            fw[fs] = w_[i]; fn[fs] = nbr[i]; slot[fs] = true; ++fs;
        }
        for (int i = 0; i < 8; ++i) nbf[ps][i] = fn[i];
        for (int t = 0; t < 256; ++t) {
            unsigned qi = 0;
            for (int i = 0; i < 8; ++i)
                if (t & (1 << i)) qi ^= fw[i];
            tb.qstore[ps][t] = (unsigned short)qi;
        }
        for (int j = 0; j < 4; ++j)
            tb.smask[ps][j] = have_lm ? lmap_apply(lm, pm[ps][j]) : pm[ps][j];
    }
    // init: writes into L_0
    {
        unsigned B[12] = {}, I[12] = {};
        for (int i = 0; i < 8; ++i) { B[i] = nbf[0][i]; I[i] = 1u << (1 + i); }
        B[8] = pm[0][0]; I[8] = 1u;
        B[9] = pm[0][1]; I[9] = 512u;
        B[10] = pm[0][2]; I[10] = 1024u;
        B[11] = pm[0][3]; I[11] = 2048u;
        const LMap lm0 = build_lmap(B, I);
        for (int t = 0; t < 256; ++t)
            tb.init_t[t] = (unsigned short)lmap_apply(lm0, (unsigned)t);
        for (int k = 0; k < 16; ++k)
            tb.initk[k] = (unsigned short)lmap_apply(lm0, (unsigned)(k << 8));
    }
    return tb;
}

__constant__ Tab GT = make_tab();

// pass-ordered Rot coefs: [pass*32 + lev*8 + j]; layer-0 at [480 + w*8 + j].
__device__ float g_coef[576];

__device__ __forceinline__ void rot8(const float* __restrict__ wp, float* o) {
    const float phi = wp[0], th = wp[1], om = wp[2];
    const float hs = 0.5f * (phi + om), hd = 0.5f * (phi - om), ht = 0.5f * th;
    const float ctt = cosf(ht), stt = sinf(ht);
    const float cs = cosf(hs), ss = sinf(hs);
    const float cd = cosf(hd), sd = sinf(hd);
    o[0] = cs * ctt;  o[1] = -ss * ctt;   // u00
    o[2] = -cd * stt; o[3] = -sd * stt;   // u01
    o[4] = cd * stt;  o[5] = -sd * stt;   // u10
    o[6] = cs * ctt;  o[7] = ss * ctt;    // u11
}

__global__ void rot_coef_kernel(const float* __restrict__ weights) {
    const int i = blockIdx.x * blockDim.x + threadIdx.x;
    if (i < 60) {
        const int ps = i >> 2, lev = i & 3;
        const int g = GT.ggate[ps][lev];
        float o[8];
        rot8(weights + g * 3, o);
        #pragma unroll
        for (int j = 0; j < 8; ++j) g_coef[ps * 32 + lev * 8 + j] = o[j];
    } else if (i >= 64 && i < 76) {
        const int w = i - 64;
        float o[8];
        rot8(weights + w * 3, o);
        #pragma unroll
        for (int j = 0; j < 8; ++j) g_coef[480 + w * 8 + j] = o[j];
    }
}

__device__ __forceinline__ v2f cmulv(v2f A, v2f B) {
    return (v2f){ A.x * B.x - A.y * B.y, A.x * B.y + A.y * B.x };
}

// packed complex butterfly (v_pk_fma_f32 path, R11)
__device__ __forceinline__ void bf(v2f& X, v2f& Y,
                                   float Ar, float Ai, float Br, float Bi,
                                   float Cr, float Ci, float Dr, float Di) {
    const v2f x = X, y = Y;
    const v2f xs = { -x.y, x.x };
    const v2f ys = { -y.y, y.x };
    v2f nx = x * (v2f){ Ar, Ar };
    nx = __builtin_elementwise_fma((v2f){ Ai, Ai }, xs, nx);
    nx = __builtin_elementwise_fma((v2f){ Br, Br }, y,  nx);
    nx = __builtin_elementwise_fma((v2f){ Bi, Bi }, ys, nx);
    v2f ny = x * (v2f){ Cr, Cr };
    ny = __builtin_elementwise_fma((v2f){ Ci, Ci }, xs, ny);
    ny = __builtin_elementwise_fma((v2f){ Dr, Dr }, y,  ny);
    ny = __builtin_elementwise_fma((v2f){ Di, Di }, ys, ny);
    X = nx; Y = ny;
}

// ---------------------------------------------------------------------------
// One block (256 threads) per batch element. LDS = exactly the 32 KB state.
// 15 passes: 8x coalesced ds_read_b128 loads, packed butterflies, b64 gray
// store chain into the NEXT pass's layout. Named registers throughout.
// ---------------------------------------------------------------------------
__global__ __launch_bounds__(256) void qvl_fused(
    const float* __restrict__ v,        // (B, 512)
    const float* __restrict__ Wc,       // (12, 512)
    const float* __restrict__ bc,       // (12,)
    float* __restrict__ out)            // (B, 12)
{
    __shared__ alignas(16) v2f st[4096];          // 32768 B total LDS
    float* redf = reinterpret_cast<float*>(st);   // overlay (48 floats)
    v4f* st4 = reinterpret_cast<v4f*>(st);

    const int t    = threadIdx.x;
    const int lane = t & 63;
    const int wv   = t >> 6;
    const int b    = blockIdx.x;

    // ---- x_w = tanh(v[b] . Wc[w] + bc[w]) * pi (partials into overlay) -----
    {
        const float2 vv = reinterpret_cast<const float2*>(v + b * 512)[t];
        #pragma unroll
        for (int w = 0; w < 12; ++w) {
            const float2 ww = reinterpret_cast<const float2*>(Wc + w * 512)[t];
            float p = vv.x * ww.x + vv.y * ww.y;
            #pragma unroll
            for (int s = 1; s < 64; s <<= 1) p += __shfl_xor(p, s, 64);
            if (lane == 0) redf[w * 4 + wv] = p;
        }
    }
    __syncthreads();

    // ---- per-wave: lanes 0..11 fold RY(x_w) + layer-0 Rot into (aw, bw) ----
    float awx = 0.0f, awy = 0.0f, bwx = 0.0f, bwy = 0.0f;
    if (lane < 12) {
        const float x = tanhf(redf[lane * 4 + 0] + redf[lane * 4 + 1] +
                              redf[lane * 4 + 2] + redf[lane * 4 + 3] + bc[lane]) * PI_F;
        const float h = 0.5f * x;
        const float c = cosf(h), s = sinf(h);
        const float* c8 = g_coef + 480 + lane * 8;
        awx = c8[0] * c + c8[2] * s;  awy = c8[1] * c + c8[3] * s;
        bwx = c8[4] * c + c8[6] * s;  bwy = c8[5] * c + c8[7] * s;
    }
    __syncthreads();   // overlay reads done before init overwrites st

    // ---- init: product state written into layout L_0 ------------------------
    {
        v2f hi = { 1.0f, 0.0f };
        #pragma unroll
        for (int j = 0; j < 8; ++j) {
            const int src = 11 - j;            // wire for p bit j
            const float ax = __shfl(awx, src, 64), ay = __shfl(awy, src, 64);
            const float bx = __shfl(bwx, src, 64), by = __shfl(bwy, src, 64);
            const int bit = (t >> j) & 1;
            hi = cmulv(hi, (v2f){ bit ? bx : ax, bit ? by : ay });
        }
        v2f A3 = { __shfl(awx, 3, 64), __shfl(awy, 3, 64) };
        v2f B3 = { __shfl(bwx, 3, 64), __shfl(bwy, 3, 64) };
        v2f A2 = { __shfl(awx, 2, 64), __shfl(awy, 2, 64) };
        v2f B2 = { __shfl(bwx, 2, 64), __shfl(bwy, 2, 64) };
        v2f A1 = { __shfl(awx, 1, 64), __shfl(awy, 1, 64) };
        v2f B1 = { __shfl(bwx, 1, 64), __shfl(bwy, 1, 64) };
        v2f A0 = { __shfl(awx, 0, 64), __shfl(awy, 0, 64) };
        v2f B0 = { __shfl(bwx, 0, 64), __shfl(bwy, 0, 64) };
        v2f fA[4], fB[4];
        #pragma unroll
        for (int m = 0; m < 4; ++m) {
            fA[m] = cmulv((m & 1) ? B3 : A3, (m & 2) ? B2 : A2);   // p bits 8,9
            fB[m] = cmulv((m & 1) ? B1 : A1, (m & 2) ? B0 : A0);   // p bits 10,11
        }
        const unsigned it = GT.init_t[t];
        #pragma unroll
        for (int k = 0; k < 16; ++k)
            st[it ^ GT.initk[k]] = cmulv(hi, cmulv(fA[k & 3], fB[k >> 2]));
    }

    // ---- 15 fused passes (layers 1..5, 4 gates each) ------------------------
    #pragma unroll 1
    for (int ps = 0; ps < 15; ++ps) {
        unsigned q = GT.qstore[ps][t];       // store base (next-pass layout)
        __syncthreads();
        const float* cp = g_coef + ps * 32;  // uniform -> s_load
        const unsigned m0 = GT.smask[ps][0], m1 = GT.smask[ps][1];
        const unsigned m2 = GT.smask[ps][2], m3 = GT.smask[ps][3];

        // coalesced b128 loads: amp(pos) at v4f index t + posHi*256
        const v4f L0v = st4[t];
        const v4f L1v = st4[t + 256];
        const v4f L2v = st4[t + 512];
        const v4f L3v = st4[t + 768];
        const v4f L4v = st4[t + 1024];
        const v4f L5v = st4[t + 1280];
        const v4f L6v = st4[t + 1536];
        const v4f L7v = st4[t + 1792];
        v2f g0  = { L0v.x, L0v.y }, g1  = { L0v.z, L0v.w };
        v2f g2  = { L1v.x, L1v.y }, g3  = { L1v.z, L1v.w };
        v2f g4  = { L2v.x, L2v.y }, g5  = { L2v.z, L2v.w };
        v2f g6  = { L3v.x, L3v.y }, g7  = { L3v.z, L3v.w };
        v2f g8  = { L4v.x, L4v.y }, g9  = { L4v.z, L4v.w };
        v2f g10 = { L5v.x, L5v.y }, g11 = { L5v.z, L5v.w };
        v2f g12 = { L6v.x, L6v.y }, g13 = { L6v.z, L6v.w };
        v2f g14 = { L7v.x, L7v.y }, g15 = { L7v.z, L7v.w };

        // all representatives have role parity 0 at every level -> raw coefs
        #define BF(X, Y) bf(X, Y, Ar, Ai, Br, Bi, Cr, Ci, Dr, Di)
        { const float Ar = cp[0],  Ai = cp[1],  Br = cp[2],  Bi = cp[3];
          const float Cr = cp[4],  Ci = cp[5],  Dr = cp[6],  Di = cp[7];
          BF(g0,g1); BF(g2,g3); BF(g4,g5); BF(g6,g7);
          BF(g8,g9); BF(g10,g11); BF(g12,g13); BF(g14,g15); }
        { const float Ar = cp[8],  Ai = cp[9],  Br = cp[10], Bi = cp[11];
          const float Cr = cp[12], Ci = cp[13], Dr = cp[14], Di = cp[15];
          BF(g0,g2); BF(g1,g3); BF(g4,g6); BF(g5,g7);
          BF(g8,g10); BF(g9,g11); BF(g12,g14); BF(g13,g15); }
        { const float Ar = cp[16], Ai = cp[17], Br = cp[18], Bi = cp[19];
          const float Cr = cp[20], Ci = cp[21], Dr = cp[22], Di = cp[23];
          BF(g0,g4); BF(g1,g5); BF(g2,g6); BF(g3,g7);
          BF(g8,g12); BF(g9,g13); BF(g10,g14); BF(g11,g15); }
        { const float Ar = cp[24], Ai = cp[25], Br = cp[26], Bi = cp[27];
          const float Cr = cp[28], Ci = cp[29], Dr = cp[30], Di = cp[31];
          BF(g0,g8); BF(g1,g9); BF(g2,g10); BF(g3,g11);
          BF(g4,g12); BF(g5,g13); BF(g6,g14); BF(g7,g15); }
        #undef BF

        __syncthreads();   // all loads done before stores scatter into st

        // gray-chain store into NEXT pass's layout
        asm volatile("" : "+v"(q));
        unsigned ad = q;
        st[ad] = g0;  ad ^= m0;
        st[ad] = g1;  ad ^= m1;
        st[ad] = g3;  ad ^= m0;
        st[ad] = g2;  ad ^= m2;
        st[ad] = g6;  ad ^= m0;
        st[ad] = g7;  ad ^= m1;
        st[ad] = g5;  ad ^= m0;
        st[ad] = g4;  ad ^= m3;
        st[ad] = g12; ad ^= m0;
        st[ad] = g13; ad ^= m1;
        st[ad] = g15; ad ^= m0;
        st[ad] = g14; ad ^= m2;
        st[ad] = g10; ad ^= m0;
        st[ad] = g11; ad ^= m1;
        st[ad] = g9;  ad ^= m0;
        st[ad] = g8;
    }
    __syncthreads();

    // ---- PauliZ expvals; layout after pass 14 is identity: addr = p --------
    float p2[16];
    #pragma unroll
    for (int k = 0; k < 16; ++k) {
        const v2f aa = st[k * 256 + t];
        p2[k] = aa.x * aa.x + aa.y * aa.y;
    }
    __syncthreads();   // all st reads done before overlay reuse
    #pragma unroll
    for (int w = 0; w < 12; ++w) {
        const unsigned zr = GT.zrow[w];
        const unsigned Aw = (unsigned)__popc((unsigned)t & zr) & 1u;
        const unsigned nm = (zr >> 8) & 0xFu;
        unsigned P = 0u;
        P ^= (nm & 1u) ? 0xAAAAu : 0u;
        P ^= (nm & 2u) ? 0xCCCCu : 0u;
        P ^= (nm & 4u) ? 0xF0F0u : 0u;
        P ^= (nm & 8u) ? 0xFF00u : 0u;
        P ^= Aw ? 0xFFFFu : 0u;
        float z = 0.0f;
        #pragma unroll
        for (int k = 0; k < 16; ++k)
            z += ((P >> k) & 1u) ? -p2[k] : p2[k];
        #pragma unroll
        for (int s = 1; s < 64; s <<= 1) z += __shfl_xor(z, s, 64);
        if (lane == 0) redf[w * 4 + wv] = z;
    }
    __syncthreads();
    if (t < 12)
        out[b * 12 + t] = redf[t * 4 + 0] + redf[t * 4 + 1] +
                          redf[t * 4 + 2] + redf[t * 4 + 3];
}

extern "C" void kernel_launch(void* const* d_in, const int* in_sizes, int n_in,
                              void* d_out, int out_size, void* d_ws, size_t ws_size,
                              hipStream_t stream) {
    (void)n_in; (void)out_size; (void)d_ws; (void)ws_size;
    const float* v   = (const float*)d_in[0];
    const float* Wc  = (const float*)d_in[1];
    const float* bc  = (const float*)d_in[2];
    const float* wts = (const float*)d_in[3];
    float* out = (float*)d_out;

    const int B = in_sizes[0] / 512;
    rot_coef_kernel<<<1, 128, 0, stream>>>(wts);
    qvl_fused<<<B, 256, 0, stream>>>(v, Wc, bc, out);
}